// Round 19
// baseline (28.821 us; speedup 1.0000x reference)
//
#include <hip/hip_runtime.h>
#include <hip/hip_bf16.h>
#include <math.h>

// Problem: B=16, K=256, D=128, H=64
//   sd[b,i,j] = sum_h gelu(hi[b,i,h] + hj[b,j,h]) * W2[h] + b2,  loss = MSE vs dist
//
// Measured ledger:
//  R7:  device-fence storm = +90us -> loss stays a separate kernel kC.
//  R10: pk f32 = scalar FLOP rate. R13: v_rcp occupies VALU (no parallel pipe).
//  R15: kA~5 (W1-traffic/TLP trap, R18: all kA variants equal), kB~16, kC~0.5.
//  R18 analysis: kB was DUAL-bound - LDS pipe is per-CU: 5 b128/iter for 4 outs
//       -> DS ~83% of VALU. R19: 32x64 tile, 8 outs/thread -> 7 b128/iter for
//       8 outs (DS ~58% of VALU) -> VALU-bound again. sd bitwise unchanged.

#define Bn 16
#define Kn 256
#define Dn 128
#define Hn 64
#define NBLK 512     // kB grid: 4 x 8 x 16

// gelu(x) ~= x * sigmoid(1.702 x); Schraudolph exp2 bits + magic-rcp + 1 NR.
// 9 VALU ops per element incl. caller's x-add and the acc fma.
__device__ __forceinline__ void gelu_acc(float x, float w, float& acc) {
    float u  = fmaf(x, -20598733.0f, 1064987473.0f);
    int   iu = (int)u;
    float e  = __builtin_bit_cast(float, iu);
    float d  = e + 1.0f;
    int   ir = 0x7EF311C3 - __builtin_bit_cast(int, d);
    float r0 = __builtin_bit_cast(float, ir);
    float r  = r0 * fmaf(-d, r0, 2.0f);
    acc = fmaf(x * r, w, acc);
}

// ---------------- Kernel A: hi/hj precompute, LDS-free, 4 rows/wave (R16) ----------------
__global__ __launch_bounds__(64) void kA(const float* __restrict__ particles,
                                         const float* __restrict__ W1,
                                         const float* __restrict__ b1,
                                         float* __restrict__ hi,
                                         float* __restrict__ hj) {
    const int hg  = threadIdx.x;               // 0..63
    const int row = blockIdx.x * 4;

    const float* __restrict__ p0 = particles + (size_t)row * Dn;
    const float* __restrict__ p1 = p0 + Dn;
    const float* __restrict__ p2 = p0 + 2 * Dn;
    const float* __restrict__ p3 = p0 + 3 * Dn;
    const float* __restrict__ wa = W1 + hg;
    const float* __restrict__ wb = W1 + Dn * Hn + hg;

    float ai0 = 0.f, ai1 = 0.f, ai2 = 0.f, ai3 = 0.f;
    float aj0 = 0.f, aj1 = 0.f, aj2 = 0.f, aj3 = 0.f;
#pragma unroll 8
    for (int d = 0; d < Dn; ++d) {
        const float va = wa[(size_t)d * Hn];
        const float vb = wb[(size_t)d * Hn];
        const float pa = p0[d];
        const float pb = p1[d];
        const float pc = p2[d];
        const float pd = p3[d];
        ai0 = fmaf(pa, va, ai0); aj0 = fmaf(pa, vb, aj0);
        ai1 = fmaf(pb, va, ai1); aj1 = fmaf(pb, vb, aj1);
        ai2 = fmaf(pc, va, ai2); aj2 = fmaf(pc, vb, aj2);
        ai3 = fmaf(pd, va, ai3); aj3 = fmaf(pd, vb, aj3);
    }
    const float bh = b1[hg];
    hi[(size_t)(row + 0) * Hn + hg] = ai0 + bh;
    hi[(size_t)(row + 1) * Hn + hg] = ai1 + bh;
    hi[(size_t)(row + 2) * Hn + hg] = ai2 + bh;
    hi[(size_t)(row + 3) * Hn + hg] = ai3 + bh;
    hj[(size_t)(row + 0) * Hn + hg] = aj0;
    hj[(size_t)(row + 1) * Hn + hg] = aj1;
    hj[(size_t)(row + 2) * Hn + hg] = aj2;
    hj[(size_t)(row + 3) * Hn + hg] = aj3;
}

// ---------------- Kernel B: 32x64 tile, 8 outputs/thread ----------------
// grid (K/64, K/32, B) = (4,8,16) = 512 blocks, 256 threads.
// Thread (ti=tid>>4, tj=tid&15): i in {ti, ti+16}, j in {tj, +16, +32, +48}.
// Per h4-iter: 7 ds_read_b128 serve 8 outputs (0.875 reads/output).
__global__ __launch_bounds__(256) void kB(const float* __restrict__ hi,
                                          const float* __restrict__ hj,
                                          const float* __restrict__ positions,
                                          const float* __restrict__ W2,
                                          const float* __restrict__ b2,
                                          float* __restrict__ out,
                                          float* __restrict__ partials) {
    __shared__ __align__(16) float shi[32][68];
    __shared__ __align__(16) float shj[64][68];
    __shared__ __align__(16) float w2s[Hn];
    __shared__ float pix[32], piy[32], pjx[64], pjy[64];
    __shared__ float wsum[4];

    const int jt = blockIdx.x, it = blockIdx.y, b = blockIdx.z;
    const int tid = threadIdx.x;
    const int bi = b * Kn + it * 32;
    const int bj = b * Kn + jt * 64;

    // stage: shi 512 float4 (2/thread), shj 1024 float4 (4/thread)
    for (int idx = tid; idx < 512; idx += 256) {
        const int rr = idx >> 4, c4 = (idx & 15) * 4;
        *(float4*)&shi[rr][c4] = *(const float4*)&hi[(bi + rr) * Hn + c4];
    }
    for (int idx = tid; idx < 1024; idx += 256) {
        const int rr = idx >> 4, c4 = (idx & 15) * 4;
        *(float4*)&shj[rr][c4] = *(const float4*)&hj[(bj + rr) * Hn + c4];
    }
    if (tid < Hn / 4)
        ((float4*)w2s)[tid] = ((const float4*)W2)[tid];
    if (tid < 32) {
        pix[tid] = positions[(bi + tid) * 2 + 0];
        piy[tid] = positions[(bi + tid) * 2 + 1];
    }
    if (tid < 64) {
        pjx[tid] = positions[(bj + tid) * 2 + 0];
        pjy[tid] = positions[(bj + tid) * 2 + 1];
    }
    const float bb = b2[0];
    __syncthreads();

    const int ti = tid >> 4, tj = tid & 15;

    float a00 = 0.f, a01 = 0.f, a02 = 0.f, a03 = 0.f;   // i=ti,    j=tj+{0,16,32,48}
    float a10 = 0.f, a11 = 0.f, a12 = 0.f, a13 = 0.f;   // i=ti+16
#pragma unroll
    for (int h = 0; h < Hn; h += 4) {
        const float4 ai0 = *(const float4*)&shi[ti][h];
        const float4 ai1 = *(const float4*)&shi[ti + 16][h];
        const float4 c0  = *(const float4*)&shj[tj][h];
        const float4 c1  = *(const float4*)&shj[tj + 16][h];
        const float4 c2  = *(const float4*)&shj[tj + 32][h];
        const float4 c3  = *(const float4*)&shj[tj + 48][h];
        const float4 w   = *(const float4*)&w2s[h];
        gelu_acc(ai0.x + c0.x, w.x, a00); gelu_acc(ai0.y + c0.y, w.y, a00);
        gelu_acc(ai0.z + c0.z, w.z, a00); gelu_acc(ai0.w + c0.w, w.w, a00);
        gelu_acc(ai0.x + c1.x, w.x, a01); gelu_acc(ai0.y + c1.y, w.y, a01);
        gelu_acc(ai0.z + c1.z, w.z, a01); gelu_acc(ai0.w + c1.w, w.w, a01);
        gelu_acc(ai0.x + c2.x, w.x, a02); gelu_acc(ai0.y + c2.y, w.y, a02);
        gelu_acc(ai0.z + c2.z, w.z, a02); gelu_acc(ai0.w + c2.w, w.w, a02);
        gelu_acc(ai0.x + c3.x, w.x, a03); gelu_acc(ai0.y + c3.y, w.y, a03);
        gelu_acc(ai0.z + c3.z, w.z, a03); gelu_acc(ai0.w + c3.w, w.w, a03);
        gelu_acc(ai1.x + c0.x, w.x, a10); gelu_acc(ai1.y + c0.y, w.y, a10);
        gelu_acc(ai1.z + c0.z, w.z, a10); gelu_acc(ai1.w + c0.w, w.w, a10);
        gelu_acc(ai1.x + c1.x, w.x, a11); gelu_acc(ai1.y + c1.y, w.y, a11);
        gelu_acc(ai1.z + c1.z, w.z, a11); gelu_acc(ai1.w + c1.w, w.w, a11);
        gelu_acc(ai1.x + c2.x, w.x, a12); gelu_acc(ai1.y + c2.y, w.y, a12);
        gelu_acc(ai1.z + c2.z, w.z, a12); gelu_acc(ai1.w + c2.w, w.w, a12);
        gelu_acc(ai1.x + c3.x, w.x, a13); gelu_acc(ai1.y + c3.y, w.y, a13);
        gelu_acc(ai1.z + c3.z, w.z, a13); gelu_acc(ai1.w + c3.w, w.w, a13);
    }

    const int i0 = it * 32 + ti, i1 = i0 + 16;
    const int j0 = jt * 64 + tj;
    const float xi0 = pix[ti], yi0 = piy[ti], xi1 = pix[ti + 16], yi1 = piy[ti + 16];

    float v = 0.0f;
    float accs0[4] = {a00, a01, a02, a03};
    float accs1[4] = {a10, a11, a12, a13};
#pragma unroll
    for (int q = 0; q < 4; ++q) {
        const float sd0 = accs0[q] + bb;
        const float sd1 = accs1[q] + bb;
        const float xj = pjx[tj + q * 16], yj = pjy[tj + q * 16];
        const float dx0 = xi0 - xj, dy0 = yi0 - yj;
        const float dx1 = xi1 - xj, dy1 = yi1 - yj;
        const float d20 = dx0 * dx0 + dy0 * dy0;
        const float d21 = dx1 * dx1 + dy1 * dy1;
        const float td0 = (d20 > 0.f) ? sqrtf(d20) : 0.f;
        const float td1 = (d21 > 0.f) ? sqrtf(d21) : 0.f;
        out[((b * Kn) + i0) * Kn + j0 + q * 16] = sd0;
        out[((b * Kn) + i1) * Kn + j0 + q * 16] = sd1;
        v += (sd0 - td0) * (sd0 - td0) + (sd1 - td1) * (sd1 - td1);
    }

    // deterministic block reduce of squared error
#pragma unroll
    for (int off = 32; off > 0; off >>= 1) v += __shfl_down(v, off);
    if ((tid & 63) == 0) wsum[tid >> 6] = v;
    __syncthreads();
    if (tid == 0) {
        const int bid = (b * gridDim.y + it) * gridDim.x + jt;
        partials[bid] = (wsum[0] + wsum[1]) + (wsum[2] + wsum[3]);
    }
}

// ---------------- Kernel C: final loss reduction (deterministic order) ----------------
__global__ __launch_bounds__(256) void kC(const float* __restrict__ partials,
                                          float* __restrict__ loss_out) {
    __shared__ float s[256];
    const int tid = threadIdx.x;
    s[tid] = partials[tid] + partials[tid + 256];      // NBLK = 512
    __syncthreads();
    for (int off = 128; off > 0; off >>= 1) {
        if (tid < off) s[tid] += s[tid + off];
        __syncthreads();
    }
    if (tid == 0)
        loss_out[0] = s[0] * (1.0f / (float)(Bn * Kn * Kn));
}

extern "C" void kernel_launch(void* const* d_in, const int* in_sizes, int n_in,
                              void* d_out, int out_size, void* d_ws, size_t ws_size,
                              hipStream_t stream) {
    const float* particles = (const float*)d_in[0];
    const float* positions = (const float*)d_in[1];
    const float* W1        = (const float*)d_in[2];
    const float* b1        = (const float*)d_in[3];
    const float* W2        = (const float*)d_in[4];
    const float* b2        = (const float*)d_in[5];

    float* out = (float*)d_out;                       // [B*K*K] sd, then [1] loss
    float* ws  = (float*)d_ws;
    float* hi       = ws;                             // B*K*H floats
    float* hj       = ws + Bn * Kn * Hn;
    float* partials = ws + 2 * Bn * Kn * Hn;          // NBLK floats

    kA<<<dim3((Bn * Kn) / 4), dim3(64), 0, stream>>>(particles, W1, b1, hi, hj);
    kB<<<dim3(Kn / 64, Kn / 32, Bn), dim3(256), 0, stream>>>(hi, hj, positions, W2, b2,
                                                             out, partials);
    kC<<<dim3(1), dim3(256), 0, stream>>>(partials, out + (size_t)Bn * Kn * Kn);
}

// Round 20
// 27.342 us; speedup vs baseline: 1.0541x; 1.0541x over previous
//
#include <hip/hip_runtime.h>
#include <hip/hip_bf16.h>
#include <math.h>

// Problem: B=16, K=256, D=128, H=64
//   sd[b,i,j] = sum_h gelu(hi[b,i,h] + hj[b,j,h]) * W2[h] + b2,  loss = MSE vs dist
//
// Measured ledger:
//  R7:  device-fence storm = +90us -> loss stays separate kernel kC.
//  R10: pk f32 = scalar FLOP rate. R13: v_rcp occupies VALU (no parallel pipe).
//  R15: kA~4.5 (traffic/TLP trap), kB~15.5, kC~0.5, gaps ~4.5.
//  R19: 8-out widening regressed (28.8) -> revert to 32x32 4-out (27.8 best).
//  R20 theory: kB VGPR_Count=32 (measured) strangles ILP -> launch_bounds(256,4)
//       (128 VGPR budget, 4 waves/SIMD) + W2 hoisted to 16 float4 registers.

#define Bn 16
#define Kn 256
#define Dn 128
#define Hn 64
#define NBLK 1024    // kB grid: 8 x 8 x 16

// gelu(x) ~= x * sigmoid(1.702 x); Schraudolph exp2 bits + magic-rcp + 1 NR.
// 9 VALU ops per element incl. caller's x-add and the acc fma.
__device__ __forceinline__ void gelu_acc(float x, float w, float& acc) {
    float u  = fmaf(x, -20598733.0f, 1064987473.0f);
    int   iu = (int)u;
    float e  = __builtin_bit_cast(float, iu);
    float d  = e + 1.0f;
    int   ir = 0x7EF311C3 - __builtin_bit_cast(int, d);
    float r0 = __builtin_bit_cast(float, ir);
    float r  = r0 * fmaf(-d, r0, 2.0f);
    acc = fmaf(x * r, w, acc);
}

// ---------------- Kernel A: hi/hj precompute, LDS-free, 4 rows/wave (R16) ----------------
__global__ __launch_bounds__(64) void kA(const float* __restrict__ particles,
                                         const float* __restrict__ W1,
                                         const float* __restrict__ b1,
                                         float* __restrict__ hi,
                                         float* __restrict__ hj) {
    const int hg  = threadIdx.x;               // 0..63
    const int row = blockIdx.x * 4;

    const float* __restrict__ p0 = particles + (size_t)row * Dn;
    const float* __restrict__ p1 = p0 + Dn;
    const float* __restrict__ p2 = p0 + 2 * Dn;
    const float* __restrict__ p3 = p0 + 3 * Dn;
    const float* __restrict__ wa = W1 + hg;
    const float* __restrict__ wb = W1 + Dn * Hn + hg;

    float ai0 = 0.f, ai1 = 0.f, ai2 = 0.f, ai3 = 0.f;
    float aj0 = 0.f, aj1 = 0.f, aj2 = 0.f, aj3 = 0.f;
#pragma unroll 8
    for (int d = 0; d < Dn; ++d) {
        const float va = wa[(size_t)d * Hn];
        const float vb = wb[(size_t)d * Hn];
        const float pa = p0[d];
        const float pb = p1[d];
        const float pc = p2[d];
        const float pd = p3[d];
        ai0 = fmaf(pa, va, ai0); aj0 = fmaf(pa, vb, aj0);
        ai1 = fmaf(pb, va, ai1); aj1 = fmaf(pb, vb, aj1);
        ai2 = fmaf(pc, va, ai2); aj2 = fmaf(pc, vb, aj2);
        ai3 = fmaf(pd, va, ai3); aj3 = fmaf(pd, vb, aj3);
    }
    const float bh = b1[hg];
    hi[(size_t)(row + 0) * Hn + hg] = ai0 + bh;
    hi[(size_t)(row + 1) * Hn + hg] = ai1 + bh;
    hi[(size_t)(row + 2) * Hn + hg] = ai2 + bh;
    hi[(size_t)(row + 3) * Hn + hg] = ai3 + bh;
    hj[(size_t)(row + 0) * Hn + hg] = aj0;
    hj[(size_t)(row + 1) * Hn + hg] = aj1;
    hj[(size_t)(row + 2) * Hn + hg] = aj2;
    hj[(size_t)(row + 3) * Hn + hg] = aj3;
}

// ---------------- Kernel B: 32x32 tile, 4 outputs/thread, wide VGPR budget ----------------
// grid (K/32, K/32, B) = (8,8,16), 256 threads; launch_bounds(256,4):
// 4 waves/SIMD min -> up to 128 VGPRs -> W2 lives in 16 float4 registers,
// gelu chains can overlap without spill-moves (R20 theory: VGPR=32 was the
// hidden 1.5x instruction overhead).
__global__ __launch_bounds__(256, 4) void kB(const float* __restrict__ hi,
                                             const float* __restrict__ hj,
                                             const float* __restrict__ positions,
                                             const float* __restrict__ W2,
                                             const float* __restrict__ b2,
                                             float* __restrict__ out,
                                             float* __restrict__ partials) {
    __shared__ __align__(16) float shi[32][68];
    __shared__ __align__(16) float shj[32][68];
    __shared__ float pix[32], piy[32], pjx[32], pjy[32];
    __shared__ float wsum[4];

    const int jt = blockIdx.x, it = blockIdx.y, b = blockIdx.z;
    const int tid = threadIdx.x;
    const int bi = b * Kn + it * 32;
    const int bj = b * Kn + jt * 32;

    for (int idx = tid; idx < 512; idx += 256) {
        const int rr = idx >> 4, c4 = (idx & 15) * 4;
        *(float4*)&shi[rr][c4] = *(const float4*)&hi[(bi + rr) * Hn + c4];
        *(float4*)&shj[rr][c4] = *(const float4*)&hj[(bj + rr) * Hn + c4];
    }
    if (tid < 32) {
        pix[tid] = positions[(bi + tid) * 2 + 0];
        piy[tid] = positions[(bi + tid) * 2 + 1];
        pjx[tid] = positions[(bj + tid) * 2 + 0];
        pjy[tid] = positions[(bj + tid) * 2 + 1];
    }
    const float bb = b2[0];

    // W2 -> 16 float4 REGISTERS (loop-invariant; 64 VGPRs, affordable at 4 waves/SIMD)
    float4 wr[16];
#pragma unroll
    for (int q = 0; q < 16; ++q)
        wr[q] = ((const float4*)W2)[q];

    __syncthreads();

    const int ti = tid >> 4, tj = tid & 15;

    float acc00 = 0.f, acc01 = 0.f, acc10 = 0.f, acc11 = 0.f;
#pragma unroll
    for (int h = 0; h < Hn; h += 4) {
        const float4 a0 = *(const float4*)&shi[ti][h];
        const float4 a1 = *(const float4*)&shi[ti + 16][h];
        const float4 c0 = *(const float4*)&shj[tj][h];
        const float4 c1 = *(const float4*)&shj[tj + 16][h];
        const float4 w  = wr[h >> 2];
        gelu_acc(a0.x + c0.x, w.x, acc00); gelu_acc(a0.y + c0.y, w.y, acc00);
        gelu_acc(a0.z + c0.z, w.z, acc00); gelu_acc(a0.w + c0.w, w.w, acc00);
        gelu_acc(a0.x + c1.x, w.x, acc01); gelu_acc(a0.y + c1.y, w.y, acc01);
        gelu_acc(a0.z + c1.z, w.z, acc01); gelu_acc(a0.w + c1.w, w.w, acc01);
        gelu_acc(a1.x + c0.x, w.x, acc10); gelu_acc(a1.y + c0.y, w.y, acc10);
        gelu_acc(a1.z + c0.z, w.z, acc10); gelu_acc(a1.w + c0.w, w.w, acc10);
        gelu_acc(a1.x + c1.x, w.x, acc11); gelu_acc(a1.y + c1.y, w.y, acc11);
        gelu_acc(a1.z + c1.z, w.z, acc11); gelu_acc(a1.w + c1.w, w.w, acc11);
    }
    const float sd00 = acc00 + bb, sd01 = acc01 + bb;
    const float sd10 = acc10 + bb, sd11 = acc11 + bb;

    const float xi0 = pix[ti], yi0 = piy[ti], xi1 = pix[ti + 16], yi1 = piy[ti + 16];
    const float xj0 = pjx[tj], yj0 = pjy[tj], xj1 = pjx[tj + 16], yj1 = pjy[tj + 16];
    const float d200 = (xi0-xj0)*(xi0-xj0) + (yi0-yj0)*(yi0-yj0);
    const float d201 = (xi0-xj1)*(xi0-xj1) + (yi0-yj1)*(yi0-yj1);
    const float d210 = (xi1-xj0)*(xi1-xj0) + (yi1-yj0)*(yi1-yj0);
    const float d211 = (xi1-xj1)*(xi1-xj1) + (yi1-yj1)*(yi1-yj1);
    const float td00 = (d200 > 0.f) ? sqrtf(d200) : 0.f;
    const float td01 = (d201 > 0.f) ? sqrtf(d201) : 0.f;
    const float td10 = (d210 > 0.f) ? sqrtf(d210) : 0.f;
    const float td11 = (d211 > 0.f) ? sqrtf(d211) : 0.f;

    const int i0 = it * 32 + ti, i1 = i0 + 16;
    const int j0 = jt * 32 + tj, j1 = j0 + 16;
    out[((b * Kn) + i0) * Kn + j0] = sd00;
    out[((b * Kn) + i0) * Kn + j1] = sd01;
    out[((b * Kn) + i1) * Kn + j0] = sd10;
    out[((b * Kn) + i1) * Kn + j1] = sd11;

    // deterministic block reduce of squared error (4 outputs)
    float v = (sd00 - td00) * (sd00 - td00) + (sd01 - td01) * (sd01 - td01)
            + (sd10 - td10) * (sd10 - td10) + (sd11 - td11) * (sd11 - td11);
#pragma unroll
    for (int off = 32; off > 0; off >>= 1) v += __shfl_down(v, off);
    if ((tid & 63) == 0) wsum[tid >> 6] = v;
    __syncthreads();
    if (tid == 0) {
        const int bid = (b * gridDim.y + it) * gridDim.x + jt;
        partials[bid] = (wsum[0] + wsum[1]) + (wsum[2] + wsum[3]);
    }
}

// ---------------- Kernel C: final loss reduction (deterministic order) ----------------
__global__ __launch_bounds__(256) void kC(const float* __restrict__ partials,
                                          float* __restrict__ loss_out) {
    __shared__ float s[256];
    const int tid = threadIdx.x;
    const float4* p4 = (const float4*)partials;        // NBLK/4 = 256 float4
    const float4 x = p4[tid];
    s[tid] = (x.x + x.y) + (x.z + x.w);
    __syncthreads();
    for (int off = 128; off > 0; off >>= 1) {
        if (tid < off) s[tid] += s[tid + off];
        __syncthreads();
    }
    if (tid == 0)
        loss_out[0] = s[0] * (1.0f / (float)(Bn * Kn * Kn));
}

extern "C" void kernel_launch(void* const* d_in, const int* in_sizes, int n_in,
                              void* d_out, int out_size, void* d_ws, size_t ws_size,
                              hipStream_t stream) {
    const float* particles = (const float*)d_in[0];
    const float* positions = (const float*)d_in[1];
    const float* W1        = (const float*)d_in[2];
    const float* b1        = (const float*)d_in[3];
    const float* W2        = (const float*)d_in[4];
    const float* b2        = (const float*)d_in[5];

    float* out = (float*)d_out;                       // [B*K*K] sd, then [1] loss
    float* ws  = (float*)d_ws;
    float* hi       = ws;                             // B*K*H floats
    float* hj       = ws + Bn * Kn * Hn;
    float* partials = ws + 2 * Bn * Kn * Hn;          // NBLK floats

    kA<<<dim3((Bn * Kn) / 4), dim3(64), 0, stream>>>(particles, W1, b1, hi, hj);
    kB<<<dim3(Kn / 32, Kn / 32, Bn), dim3(256), 0, stream>>>(hi, hj, positions, W2, b2,
                                                             out, partials);
    kC<<<dim3(1), dim3(256), 0, stream>>>(partials, out + (size_t)Bn * Kn * Kn);
}